// Round 3
// baseline (120.294 us; speedup 1.0000x reference)
//
#include <hip/hip_runtime.h>
#include <stdint.h>

#define T_LEN 262144
#define S 64
#define SP1 65

// forward: 16 outputs + 4 warm-up per chain, TWO chains per wave (ILP at
// UNCHANGED wave count: 16384 chains -> 8192 waves -> 2048 blocks of 256,
// 8 blocks/CU = 32 waves/CU). Loops deliberately NOT unrolled (#pragma
// unroll 1): the old 36x-inlined step body (~20KB) thrashed L1I.
#define L_FWD 16
#define W_FWD 4
#define C_FWD (T_LEN / L_FWD)    // 16384 chunks
#define C_PER_XCD (C_FWD / 8)    // 2048 chunks -> 2 MiB bp4 slice per XCD

// backtrack: one THREAD per window, LB=8 outputs, VB=8 warm chase.
// 512 blocks x 64 threads: spread over ALL 256 CUs (old 128x256 left half
// the CUs idle and stacked 4 serial chase-waves on each active CU).
#define LB2 8
#define VB2 8
#define NW (T_LEN / LB2)         // 32768 windows
#define K2_TPB 64
#define K2_BLK (NW / K2_TPB)     // 512 blocks
#define PITCH (LB2 + 2)

// DPP cumulative u32-min step (old = own value, bound_ctrl=false). After
// shr1,2,4,8 + bcast15 + bcast31, lane 63 holds the wave-wide min.
template <int CTRL>
__device__ __forceinline__ unsigned int dpp_umin_step(unsigned int v) {
    unsigned int t = (unsigned int)__builtin_amdgcn_update_dpp(
        (int)v, (int)v, CTRL, 0xf, 0xf, false);
    return min(t, v);
}

__device__ __forceinline__ float readlane_f(float v, int lane) {
    return __int_as_float(__builtin_amdgcn_readlane(__float_as_int(v), lane));
}

// packed argmax key: all scores < 0 -> u32-min on raw bits == float-max;
// low 6 bits carry j, tie-break = first occurrence (smaller j).
__device__ __forceinline__ unsigned int pack_key(float a, int j) {
    return (__float_as_uint(a) & 0xFFFFFFC0u) | (unsigned)j;
}

struct Ch {
    float delta, ll_cur, ll_nxt;
    int vroll, idx;
};

// k1: chunked forward Viterbi, two chains per wave, rolled loops.
// strans staged as fp32 (16 KB LDS; 2-way b32 reads are conflict-free).
// Per-block Mc (column bound): Mc[j] = min_i(rowmin_i - trans[i][j]) <= 0;
// winner j of any row satisfies c_j >= cmax + Mc[j]. Packed-key u32-min
// DPP reduce gives (cmax, jm) in one chain; survivors usually ~1-2.
// XCD-swizzled chunk ownership: XCD g%8 writes chunks [x*2048,(x+1)*2048).
__global__ __launch_bounds__(256, 8) void k1_forward(
    const int* __restrict__ rolls, const float* __restrict__ trans,
    const float* __restrict__ ll,
    unsigned int* __restrict__ bp4, int* __restrict__ wsFinal,
    float* __restrict__ out_score) {
    __shared__ float strans_f[S * S];  // strans_f[j*64 + i] = trans[i][j]
    __shared__ float srowmin[S];
    __shared__ float sMc[S];
    const int tid = threadIdx.x;
    const int lane = tid & 63;
    const int wv = tid >> 6;

    if (blockIdx.x == 0 && tid == 0)
        out_score[0] = 0.0f;  // k2 is stream-ordered after k1 -> safe

    for (int k = tid; k < S * S; k += 256)
        strans_f[k] = trans[(k & 63) * SP1 + (k >> 6)];
    __syncthreads();

    // per-block Mc: rowmin_i = min_j trans[i][j]; Mc[j] = min_i(rowmin_i - trans[i][j])
    {
        int i = tid >> 2, q = tid & 3;
        float mn = 3.0e38f;
        #pragma unroll
        for (int u = 0; u < 16; ++u)
            mn = fminf(mn, strans_f[((q * 16 + u) << 6) | i]);
        mn = fminf(mn, __shfl_xor(mn, 1));
        mn = fminf(mn, __shfl_xor(mn, 2));
        if (q == 0) srowmin[i] = mn;
    }
    __syncthreads();
    {
        int j = tid >> 2, q = tid & 3;
        float mc = 3.0e38f;
        #pragma unroll
        for (int u = 0; u < 16; ++u) {
            int i = q * 16 + u;
            mc = fminf(mc, srowmin[i] - strans_f[(j << 6) | i]);
        }
        mc = fminf(mc, __shfl_xor(mc, 1));
        mc = fminf(mc, __shfl_xor(mc, 2));
        if (q == 0) sMc[j] = mc;
    }
    __syncthreads();
    const float mcol = sMc[lane];

    // chains: XCD x = g%8 owns chunks [x*2048, (x+1)*2048); 8 chains/block
    const int cA = (blockIdx.x & 7) * C_PER_XCD + (blockIdx.x >> 3) * 8 + wv * 2;
    const int cB = cA + 1;

    Ch A, B;
    auto init = [&](Ch& C, int c) {
        int t0 = c * L_FWD - W_FWD;
        if (t0 < 1) t0 = 1;
        C.vroll = rolls[min(t0 + lane, T_LEN - 1)];
        if (c == 0)
            C.delta = trans[lane * SP1 + S] + ll[rolls[0] * S + lane];  // exact
        else
            C.delta = 0.0f;  // arbitrary; warm-up coalesces (additive const)
        int r0 = __builtin_amdgcn_readlane(C.vroll, 0);
        int r1 = __builtin_amdgcn_readlane(C.vroll, 1);
        C.ll_cur = ll[r0 * S + lane];
        C.ll_nxt = ll[r1 * S + lane];
        C.idx = 0;
    };
    init(A, cA);
    init(B, cB);

    auto argmax_red = [&](float cvec) -> unsigned int {
        unsigned int kv = pack_key(cvec, lane);
        kv = dpp_umin_step<0x111>(kv);
        kv = dpp_umin_step<0x112>(kv);
        kv = dpp_umin_step<0x114>(kv);
        kv = dpp_umin_step<0x118>(kv);
        kv = dpp_umin_step<0x142>(kv);
        kv = dpp_umin_step<0x143>(kv);
        return (unsigned int)__builtin_amdgcn_readlane((int)kv, 63);
    };

    // survivor finish for one chain (leader gather+ballot already hoisted
    // by pair(); this handles the conditional tail + state rotation)
    auto tail = [&](Ch& C, float cvec, unsigned long long mask,
                    unsigned int m, float ll_new) -> unsigned int {
        if (mask) {  // wave-uniform; ~1 extra survivor typical
            int j1 = __ffsll(mask) - 1;
            unsigned long long rm = mask & (mask - 1);
            float a1 = strans_f[(j1 << 6) | lane] + readlane_f(cvec, j1);
            m = min(m, pack_key(a1, j1));
            while (rm) {  // rare (>2 survivors)
                int j = __ffsll(rm) - 1;
                rm &= (rm - 1);
                float a = strans_f[(j << 6) | lane] + readlane_f(cvec, j);
                m = min(m, pack_key(a, j));
            }
        }
        C.delta = __uint_as_float(m & 0xFFFFFFC0u);  // quantized (~2^-15 rel)
        C.ll_cur = C.ll_nxt;
        C.ll_nxt = ll_new;
        C.idx++;
        return m;
    };

    // fused step of both chains: both DPP reduces interleave, both leader
    // LDS gathers issue before either ballot/survivor branch.
    auto pair = [&](unsigned int& mA, unsigned int& mB) {
        float cva = A.delta + A.ll_cur;
        float cvb = B.delta + B.ll_cur;
        unsigned int ka = argmax_red(cva);
        unsigned int kb = argmax_red(cvb);
        int rpa = __builtin_amdgcn_readlane(A.vroll, A.idx + 2);
        int rpb = __builtin_amdgcn_readlane(B.vroll, B.idx + 2);
        float lna = ll[rpa * S + lane];
        float lnb = ll[rpb * S + lane];
        int jma = (int)(ka & 63u), jmb = (int)(kb & 63u);
        float h0a = strans_f[(jma << 6) | lane];
        float h0b = strans_f[(jmb << 6) | lane];
        float thra = __uint_as_float(ka & 0xFFFFFFC0u) + mcol;
        float thrb = __uint_as_float(kb & 0xFFFFFFC0u) + mcol;
        unsigned long long ma_ = __ballot(cva >= thra) & ~(1ull << jma);
        unsigned long long mb_ = __ballot(cvb >= thrb) & ~(1ull << jmb);
        unsigned int pa = pack_key(h0a + readlane_f(cva, jma), jma);
        unsigned int pb = pack_key(h0b + readlane_f(cvb, jmb), jmb);
        mA = tail(A, cva, ma_, pa, lna);
        mB = tail(B, cvb, mb_, pb, lnb);
    };

    auto one = [&](Ch& C) -> unsigned int {
        float cv = C.delta + C.ll_cur;
        unsigned int k = argmax_red(cv);
        int rp = __builtin_amdgcn_readlane(C.vroll, C.idx + 2);
        float ln = ll[rp * S + lane];
        int jm = (int)(k & 63u);
        float h0 = strans_f[(jm << 6) | lane];
        float thr = __uint_as_float(k & 0xFFFFFFC0u) + mcol;
        unsigned long long mk = __ballot(cv >= thr) & ~(1ull << jm);
        unsigned int p = pack_key(h0 + readlane_f(cv, jm), jm);
        return tail(C, cv, mk, p, ln);
    };

    const bool a0 = (cA == 0);  // block 0 wave 0 only

    // warm-up: W_FWD steps (chain A skips entirely when exact-initialized)
    if (!a0) {
        #pragma unroll 1
        for (int w = 0; w < W_FWD; ++w) {
            unsigned int ma, mb;
            pair(ma, mb);
        }
    } else {
        #pragma unroll 1
        for (int w = 0; w < W_FWD; ++w)
            (void)one(B);
    }

    // main: 4 dwords per chain, one store per dword (no pk[] burst)
    #pragma unroll 1
    for (int q = 0; q < 4; ++q) {
        unsigned int pA = 0u, pB = 0u;
        #pragma unroll 1
        for (int u = 0; u < 4; ++u) {
            if (a0 && q == 0 && u == 0) {
                // c==0 starts at t=1: byte 0 of dword 0 never read by k2
                unsigned int mb = one(B);
                pB = (pB >> 8) | ((mb & 63u) << 24);
            } else {
                unsigned int ma, mb;
                pair(ma, mb);
                pA = (pA >> 8) | ((ma & 63u) << 24);
                pB = (pB >> 8) | ((mb & 63u) << 24);
            }
        }
        bp4[(unsigned)((cA * 4 + q) << 6) | (unsigned)lane] = pA;
        bp4[(unsigned)((cB * 4 + q) << 6) | (unsigned)lane] = pB;
    }

    if (cB == C_FWD - 1) {
        float fmx = B.delta;
        for (int off = 32; off; off >>= 1)
            fmx = fmaxf(fmx, __shfl_xor(fmx, off));
        unsigned long long em = __ballot(B.delta == fmx);
        if (lane == 0)
            *wsFinal = __ffsll(em) - 1;
    }
}

// k2: one THREAD per window. Chase 15 dependent gathers from te=thi+VB2
// (single seed; bp columns concentrate on ~2 survivors so backward chains
// coalesce inside VB2=8), record s[tlo..thi+1] in LDS, write the path,
// then score own window with neighbor-stitched boundary; one atomic/block.
// 64-thread blocks spread over all CUs; window group swizzle matches k1's
// chunk swizzle so gathers hit the bp4 slice homed on the block's XCD.
// Scoring uses fp32 tables -> returned score is exact for the emitted path.
__global__ __launch_bounds__(64) void k2_backtrack(
    const unsigned int* __restrict__ bp4, const int* __restrict__ wsFinal,
    const int* __restrict__ rolls, const float* __restrict__ trans,
    const float* __restrict__ ll, float* __restrict__ out_path,
    float* __restrict__ out_score) {
    __shared__ int sst[K2_TPB * PITCH];
    const int tid = threadIdx.x;
    // block B -> window group wb with home XCD == B%8:
    // group wb covers t in [wb*512, ...), chunk wb*32, home XCD wb/64.
    const int wb = (blockIdx.x & 7) * (K2_BLK / 8) + (blockIdx.x >> 3);
    const int b = wb * K2_TPB + tid;        // window id
    const int tlo = b * LB2;
    const int thi = tlo + LB2 - 1;
    int te = thi + VB2;
    int s;
    if (te >= T_LEN - 1) {
        te = T_LEN - 1;
        s = *wsFinal;   // exact seed for the tail windows
    } else {
        s = 0;          // arbitrary; chase coalesces
    }
    int* row = sst + tid * PITCH;
    #pragma unroll
    for (int u = 0; u < LB2 + VB2 - 1; ++u) {  // 15 dependent gathers max
        int t = te - u;
        if (t > tlo) {
            if (t <= thi + 1) row[t - tlo] = s;
            unsigned int w = bp4[((unsigned)(t >> 2) << 6) | (unsigned)s];
            s = (int)((w >> ((t & 3) << 3)) & 63u);
        }
    }
    row[0] = s;  // state at tlo
    __syncthreads();

    // path write: out[T-1-t] = s_t for t in [tlo, thi]
    #pragma unroll
    for (int u = 0; u < LB2; ++u)
        out_path[T_LEN - 1 - (tlo + u)] = (float)row[u];

    // score terms: t in [tlo+1, thi+1] (clamped to T-1):
    //   trans[s_t][s_{t-1}] + ll[rolls[t]][s_{t-1}]
    // boundary s_{thi+1}: neighbor thread's row[0]; last thread of block
    // uses own chase state at thi+1 (same convergence quality).
    float acc = 0.0f;
    #pragma unroll
    for (int u = 1; u <= LB2; ++u) {
        int t = tlo + u;
        if (t <= T_LEN - 1) {
            int sp = row[u - 1];
            int st = (u == LB2)
                         ? ((tid < K2_TPB - 1) ? sst[(tid + 1) * PITCH] : row[LB2])
                         : row[u];
            acc += trans[st * SP1 + sp] + ll[rolls[t] * S + sp];
        }
    }
    if (b == 0) {  // init term
        int s0 = row[0];
        acc += trans[s0 * SP1 + S] + ll[rolls[0] * S + s0];
    }

    for (int off = 32; off; off >>= 1)
        acc += __shfl_xor(acc, off);
    if (tid == 0)
        atomicAdd(out_score, acc);
}

extern "C" void kernel_launch(void* const* d_in, const int* in_sizes, int n_in,
                              void* d_out, int out_size, void* d_ws, size_t ws_size,
                              hipStream_t stream) {
    const int* rolls = (const int*)d_in[0];
    const float* trans = (const float*)d_in[1];   // (64, 65)
    const float* ll = (const float*)d_in[2];      // (128, 64)
    float* out = (float*)d_out;                   // [0..T): path (reverse), [T]: score
    char* ws = (char*)d_ws;
    int* wsFinal = (int*)(ws + 8);
    unsigned int* bp4 = (unsigned int*)(ws + 2048); // 16 MiB packed bp

    k1_forward<<<C_FWD / 8, 256, 0, stream>>>(rolls, trans, ll, bp4, wsFinal,
                                              out + T_LEN);
    k2_backtrack<<<K2_BLK, K2_TPB, 0, stream>>>(bp4, wsFinal, rolls, trans, ll,
                                                out, out + T_LEN);
}